// Round 9
// baseline (423.503 us; speedup 1.0000x reference)
//
#include <hip/hip_runtime.h>

typedef __attribute__((ext_vector_type(8))) short short8;
typedef __attribute__((ext_vector_type(4))) float f32x4;
typedef __attribute__((ext_vector_type(4))) int i32x4;
typedef __attribute__((ext_vector_type(2))) unsigned u32x2;

#define LOG2E 1.44269504f

__device__ __forceinline__ short f2bf(float f) {
  unsigned u = __builtin_bit_cast(unsigned, f);
  u += 0x7fffu + ((u >> 16) & 1u);   // round-to-nearest-even
  return (short)(u >> 16);
}

// ---------------- fused prologue (round-2 version) ----------------
__global__ __launch_bounds__(256) void gat_pro(
    const float* __restrict__ feat, const float* __restrict__ W,
    const float* __restrict__ a1, const float* __restrict__ a2,
    short* __restrict__ featB, short* __restrict__ WB,
    float* __restrict__ AxL, float* __restrict__ AyL) {
  __shared__ __align__(16) float a1f[256], a2f[256];
  __shared__ __align__(16) float w1f[256], w2f[256];
  __shared__ __align__(16) float tile[32][260];
  const int tid = threadIdx.x;
  const int f = blockIdx.x, b = blockIdx.y;

  a1f[tid] = a1[tid];
  a2f[tid] = a2[tid];
  __syncthreads();

  {
    float s1 = 0.f, s2 = 0.f;
    const float4* wr = (const float4*)(W + (size_t)tid * 256);
    for (int d0 = 0; d0 < 64; ++d0) {
      float4 v = wr[d0];
      s1 += v.x * a1f[d0 * 4] + v.y * a1f[d0 * 4 + 1] + v.z * a1f[d0 * 4 + 2] + v.w * a1f[d0 * 4 + 3];
      s2 += v.x * a2f[d0 * 4] + v.y * a2f[d0 * 4 + 1] + v.z * a2f[d0 * 4 + 2] + v.w * a2f[d0 * 4 + 3];
    }
    w1f[tid] = s1;
    w2f[tid] = s2;
  }
  __syncthreads();

  {
    const int r = tid >> 3, g8 = tid & 7;
    const float* frow = feat + ((size_t)(b * 4096 + f * 32 + r)) * 256;
    float s1 = 0.f, s2 = 0.f;
#pragma unroll
    for (int k = 0; k < 8; ++k) {
      const int c4 = g8 + 8 * k;
      float4 v = *(const float4*)(frow + c4 * 4);
      float4 u1 = *(const float4*)&w1f[c4 * 4];
      float4 u2 = *(const float4*)&w2f[c4 * 4];
      s1 += v.x * u1.x + v.y * u1.y + v.z * u1.z + v.w * u1.w;
      s2 += v.x * u2.x + v.y * u2.y + v.z * u2.z + v.w * u2.w;
      *(float4*)&tile[r][c4 * 4] = v;
    }
#pragma unroll
    for (int off = 4; off >= 1; off >>= 1) {
      s1 += __shfl_xor(s1, off);
      s2 += __shfl_xor(s2, off);
    }
    if (g8 == 0) {
      AxL[b * 4096 + f * 32 + r] = s1 * LOG2E;
      AyL[b * 4096 + f * 32 + r] = s2 * LOG2E;
    }
  }
  __syncthreads();

  {
    const int g = tid >> 4, l15 = tid & 15;
    short* d = featB + (((size_t)((b * 128 + f) * 16 + g)) * 64) * 8;
#pragma unroll
    for (int q = 0; q < 4; ++q) {
      short8 v;
#pragma unroll
      for (int j8 = 0; j8 < 8; ++j8) v[j8] = f2bf(tile[q * 8 + j8][g * 16 + l15]);
      *(short8*)(d + (q * 16 + l15) * 8) = v;
    }
  }

  if (b == 0 && f < 8) {
    const int g = tid >> 4, l15 = tid & 15;
    const float* s = W + ((size_t)f * 32) * 256 + g * 16 + l15;
    short* d = WB + (((size_t)(f * 16 + g)) * 64) * 8;
#pragma unroll
    for (int q = 0; q < 4; ++q) {
      short8 v;
#pragma unroll
      for (int j8 = 0; j8 < 8; ++j8) v[j8] = f2bf(s[(q * 8 + j8) * 256]);
      *(short8*)(d + (q * 16 + l15) * 8) = v;
    }
  }
}

// -------- fused softmax(mask(lrelu(rank1)))@feat @W +ELU --------
// Round-6/8 structure with HALVED superstep count: 8 windows of 512 j
// (was 16x256). All data-path levers (adj BW, featB BW, featB latency)
// have been tested neutral; the residual ~8k cyc/superstep is FIXED
// overhead (2 barrier rendezvous at 2 waves/SIMD + the chip-synchronized
// 16 MB adj burst whose drain time lands once per superstep). Doubling
// per-superstep work amortizes that overhead 2x. Pbuf[2][64][520] = 133 KB
// dynamic LDS (1 block/CU, launch_bounds(512,1)); raw s_barrier +
// lgkmcnt(0) in-loop (no vmcnt drain); 1-deep adj prefetch; featB direct
// loads (round-6 style); epilogue unchanged.
extern "C" __global__ __launch_bounds__(512, 1) void gat_attn(
    const short* __restrict__ featB,  // [4][128][16][64][8] bf16 fragments
    const int* __restrict__ adj,      // [4][4096][4096]
    const float* __restrict__ AxL, const float* __restrict__ AyL,
    const short* __restrict__ WB,     // [8][16][64][8] bf16 fragments
    float* __restrict__ out)          // [4][4096][256] f32
{
  extern __shared__ short smem[];   // Pbuf[2][64][520]; later aliased hbuf[64][264]
  __shared__ float mred[8];

  const int tid = threadIdx.x;
  const int blk = blockIdx.x;
  const int x = blk & 7;
  const int b = x >> 1;                       // XCD-pinned batch
  const int it = ((blk >> 3) << 1) | (x & 1); // 0..63
  const int i0 = it << 6;
  const int scoff = (blk >> 3) & 7;           // staggered 512-j window start

  const int lane = tid & 63;
  const int aw = tid >> 6;                    // wave 0..7

  // ---- per-batch max of AxL ----
  const float* axb = AxL + b * 4096;
  float mx = -3.4e38f;
  for (int i = tid; i < 4096; i += 512) mx = fmaxf(mx, axb[i]);
#pragma unroll
  for (int off = 32; off >= 1; off >>= 1) mx = fmaxf(mx, __shfl_xor(mx, off));
  if (lane == 0) mred[aw] = mx;
  __syncthreads();
  const float MbLb = fmaxf(fmaxf(fmaxf(mred[0], mred[1]), fmaxf(mred[2], mred[3])),
                           fmaxf(fmaxf(mred[4], mred[5]), fmaxf(mred[6], mred[7])));

  // --- P-producer role: wave owns rows aw*8..aw*8+7; lane owns 4 j's/chunk ---
  float aLk[8], ddk[8];
#pragma unroll
  for (int k = 0; k < 8; ++k) {
    float ayL = AyL[b * 4096 + i0 + aw * 8 + k];
    float sL = ayL + MbLb;
    float mrL = fmaxf(sL, 0.2f * sL);
    aLk[k] = ayL - mrL;
    ddk[k] = -0.8f * mrL;
  }
  const int* adjr = adj + ((size_t)(b * 4096 + i0 + aw * 8)) * 4096 + lane * 4;
  const float4* axp = (const float4*)(AxL + b * 4096) + lane;

  // --- MFMA role: wave owns col-tiles g in {2*aw, 2*aw+1}, all 4 row-groups ---
  const int cg2 = aw << 1;
  const int l15 = lane & 15;
  const int q = lane >> 4;

  f32x4 acc[4][2], lac[4];
#pragma unroll
  for (int r = 0; r < 4; ++r) {
    lac[r] = (f32x4){0.f, 0.f, 0.f, 0.f};
#pragma unroll
    for (int j = 0; j < 2; ++j) acc[r][j] = (f32x4){0.f, 0.f, 0.f, 0.f};
  }

  short8 ones;
#pragma unroll
  for (int j = 0; j < 8; ++j) ones[j] = (short)0x3F80;  // bf16 1.0

  const short* fbb = featB + (size_t)b * 128 * 16 * 64 * 8 + lane * 8;

  // adv[k*2+c]: row k, 256-chunk c of the current 512-j window (64 VGPR)
  i32x4 adv[16];
  float4 axv0, axv1;

  // ---- pre-loop: prefetch window scoff (adj rows x 2 chunks + Ax) ----
  {
    const int w = scoff;
    axv0 = axp[w * 128];
    axv1 = axp[w * 128 + 64];
#pragma unroll
    for (int k = 0; k < 8; ++k) {
      adv[k * 2 + 0] = __builtin_nontemporal_load((const i32x4*)(adjr) + (size_t)k * 1024 + w * 128);
      adv[k * 2 + 1] = __builtin_nontemporal_load((const i32x4*)(adjr) + (size_t)k * 1024 + w * 128 + 64);
    }
  }

  for (int sc = 0; sc < 8; ++sc) {
    const int wsc = (scoff + sc) & 7;         // actual 512-j window
    const int pb = (sc & 1) * 33280;          // Pbuf half (shorts)
    // ---- phase 1: 64 probs (8 rows x 2 chunks x 4 j) -> Pbuf ----
    {
#pragma unroll
      for (int k = 0; k < 8; ++k) {
#pragma unroll
        for (int c = 0; c < 2; ++c) {
          const float* af = (c == 0) ? (const float*)&axv0 : (const float*)&axv1;
          const i32x4 ad = adv[k * 2 + c];
          unsigned pr[4];
#pragma unroll
          for (int u = 0; u < 4; ++u) {
            float v = af[u] + aLk[k];
            float uu = fmaxf(v, fmaf(0.2f, v, ddk[k]));
            unsigned ub = ad[u] > 0 ? __builtin_bit_cast(unsigned, uu) : 0xFF800000u;
            float p = __builtin_amdgcn_exp2f(__builtin_bit_cast(float, ub));
            pr[u] = __builtin_bit_cast(unsigned, p) + 0x8000u;
          }
          u32x2 pw;
          pw[0] = __builtin_amdgcn_perm(pr[1], pr[0], 0x07060302u);
          pw[1] = __builtin_amdgcn_perm(pr[3], pr[2], 0x07060302u);
          *(u32x2*)(smem + pb + (aw * 8 + k) * 520 + c * 256 + lane * 4) = pw;
        }
      }
    }
    asm volatile("s_waitcnt lgkmcnt(0)" ::: "memory");
    __builtin_amdgcn_s_barrier();   // raw: in-flight vmem survives

    // ---- prefetch next window's adj + Ax (hidden under phase 2) ----
    if (sc < 7) {
      const int wn = (scoff + sc + 1) & 7;
      axv0 = axp[wn * 128];
      axv1 = axp[wn * 128 + 64];
#pragma unroll
      for (int k = 0; k < 8; ++k) {
        adv[k * 2 + 0] = __builtin_nontemporal_load((const i32x4*)(adjr) + (size_t)k * 1024 + wn * 128);
        adv[k * 2 + 1] = __builtin_nontemporal_load((const i32x4*)(adjr) + (size_t)k * 1024 + wn * 128 + 64);
      }
    }

    // ---- phase 2: 16 k-steps; each featB fragment loaded once per block ----
#pragma unroll
    for (int h = 0; h < 16; ++h) {
      const int f = wsc * 16 + h;
      const short* fb = fbb + (((size_t)f * 16 + cg2) << 9);
      short8 a[4];
#pragma unroll
      for (int r = 0; r < 4; ++r)
        a[r] = *(const short8*)(smem + pb + (r * 16 + l15) * 520 + h * 32 + q * 8);
#pragma unroll
      for (int r = 0; r < 4; ++r)
        lac[r] = __builtin_amdgcn_mfma_f32_16x16x32_bf16(a[r], ones, lac[r], 0, 0, 0);
#pragma unroll
      for (int ct = 0; ct < 2; ++ct) {
        short8 bf = *(const short8*)(fb + (ct << 9));
#pragma unroll
        for (int r = 0; r < 4; ++r)
          acc[r][ct] = __builtin_amdgcn_mfma_f32_16x16x32_bf16(a[r], bf, acc[r][ct], 0, 0, 0);
      }
    }
  }

  // lac[r][reg] = row-sum for row r*16 + q*4 + reg (C/D layout)
  float linv[4][4];
#pragma unroll
  for (int r = 0; r < 4; ++r)
#pragma unroll
    for (int reg = 0; reg < 4; ++reg) {
      float l = lac[r][reg];
      linv[r][reg] = l > 0.f ? 1.f / l : 0.f;
    }

  __syncthreads();   // full barrier (incl. drain) before aliasing smem as hbuf
  short* hbuf = smem;  // [64][264]
#pragma unroll
  for (int r = 0; r < 4; ++r)
#pragma unroll
    for (int reg = 0; reg < 4; ++reg) {
      const int lr = r * 16 + q * 4 + reg;
#pragma unroll
      for (int ct = 0; ct < 2; ++ct)
        hbuf[lr * 264 + (cg2 + ct) * 16 + l15] = f2bf(acc[r][ct][reg] * linv[r][reg]);
    }
  __syncthreads();

  // ---- epilogue GEMM: (64x256) @ W, ELU, store ----
  const int rowg = (aw & 1) << 4;    // 0/16; second group is +32
  const int cgrp = (aw >> 1) << 2;   // col-group base in 16-col units

  f32x4 ac2[2][4];
#pragma unroll
  for (int r = 0; r < 2; ++r)
#pragma unroll
    for (int j = 0; j < 4; ++j) ac2[r][j] = (f32x4){0.f, 0.f, 0.f, 0.f};

  const short* wbb = WB + lane * 8;
#pragma unroll
  for (int f = 0; f < 8; ++f) {
    short8 a0 = *(const short8*)&hbuf[(rowg + l15) * 264 + f * 32 + q * 8];
    short8 a1 = *(const short8*)&hbuf[(rowg + 32 + l15) * 264 + f * 32 + q * 8];
    const short* wb = wbb + (((size_t)f * 16 + cgrp) << 9);
#pragma unroll
    for (int ct = 0; ct < 4; ++ct) {
      short8 bf = *(const short8*)(wb + (ct << 9));
      ac2[0][ct] = __builtin_amdgcn_mfma_f32_16x16x32_bf16(a0, bf, ac2[0][ct], 0, 0, 0);
      ac2[1][ct] = __builtin_amdgcn_mfma_f32_16x16x32_bf16(a1, bf, ac2[1][ct], 0, 0, 0);
    }
  }

#pragma unroll
  for (int r = 0; r < 2; ++r)
#pragma unroll
    for (int reg = 0; reg < 4; ++reg) {
      const int row = i0 + rowg + r * 32 + q * 4 + reg;
      float* orow = out + ((size_t)(b * 4096 + row)) * 256 + cgrp * 16 + l15;
#pragma unroll
      for (int ct = 0; ct < 4; ++ct) {
        float v = ac2[r][ct][reg];
        float o = v > 0.f ? v : (__builtin_amdgcn_exp2f(v * LOG2E) - 1.f);
        __builtin_nontemporal_store(o, orow + ct * 16);
      }
    }
}

extern "C" void kernel_launch(void* const* d_in, const int* in_sizes, int n_in,
                              void* d_out, int out_size, void* d_ws, size_t ws_size,
                              hipStream_t stream) {
  (void)in_sizes; (void)n_in; (void)out_size; (void)ws_size;
  const float* feat = (const float*)d_in[0];
  const int* adj = (const int*)d_in[1];
  const float* W = (const float*)d_in[2];
  const float* a1 = (const float*)d_in[3];
  const float* a2 = (const float*)d_in[4];
  float* out = (float*)d_out;

  char* ws = (char*)d_ws;
  short* featB   = (short*)ws;                     // 4*128*16*64*8*2 = 8,388,608 B
  short* WB      = (short*)(ws + 8388608);         // 131,072 B
  float* AxL     = (float*)(ws + 8519680);         // 64 KB
  float* AyL     = (float*)(ws + 8585216);         // 64 KB

  hipLaunchKernelGGL(gat_pro, dim3(128, 4), dim3(256), 0, stream, feat, W, a1, a2, featB, WB, AxL, AyL);
  hipLaunchKernelGGL(gat_attn, dim3(256), dim3(512), 133120, stream, featB, adj, AxL, AyL, WB, out);
}

// Round 10
// 411.880 us; speedup vs baseline: 1.0282x; 1.0282x over previous
//
#include <hip/hip_runtime.h>

typedef __attribute__((ext_vector_type(8))) short short8;
typedef __attribute__((ext_vector_type(4))) float f32x4;
typedef __attribute__((ext_vector_type(4))) int i32x4;
typedef __attribute__((ext_vector_type(2))) unsigned u32x2;

#define LOG2E 1.44269504f

__device__ __forceinline__ short f2bf(float f) {
  unsigned u = __builtin_bit_cast(unsigned, f);
  u += 0x7fffu + ((u >> 16) & 1u);   // round-to-nearest-even
  return (short)(u >> 16);
}

// ---------------- fused prologue (round-2 version) ----------------
__global__ __launch_bounds__(256) void gat_pro(
    const float* __restrict__ feat, const float* __restrict__ W,
    const float* __restrict__ a1, const float* __restrict__ a2,
    short* __restrict__ featB, short* __restrict__ WB,
    float* __restrict__ AxL, float* __restrict__ AyL) {
  __shared__ __align__(16) float a1f[256], a2f[256];
  __shared__ __align__(16) float w1f[256], w2f[256];
  __shared__ __align__(16) float tile[32][260];
  const int tid = threadIdx.x;
  const int f = blockIdx.x, b = blockIdx.y;

  a1f[tid] = a1[tid];
  a2f[tid] = a2[tid];
  __syncthreads();

  {
    float s1 = 0.f, s2 = 0.f;
    const float4* wr = (const float4*)(W + (size_t)tid * 256);
    for (int d0 = 0; d0 < 64; ++d0) {
      float4 v = wr[d0];
      s1 += v.x * a1f[d0 * 4] + v.y * a1f[d0 * 4 + 1] + v.z * a1f[d0 * 4 + 2] + v.w * a1f[d0 * 4 + 3];
      s2 += v.x * a2f[d0 * 4] + v.y * a2f[d0 * 4 + 1] + v.z * a2f[d0 * 4 + 2] + v.w * a2f[d0 * 4 + 3];
    }
    w1f[tid] = s1;
    w2f[tid] = s2;
  }
  __syncthreads();

  {
    const int r = tid >> 3, g8 = tid & 7;
    const float* frow = feat + ((size_t)(b * 4096 + f * 32 + r)) * 256;
    float s1 = 0.f, s2 = 0.f;
#pragma unroll
    for (int k = 0; k < 8; ++k) {
      const int c4 = g8 + 8 * k;
      float4 v = *(const float4*)(frow + c4 * 4);
      float4 u1 = *(const float4*)&w1f[c4 * 4];
      float4 u2 = *(const float4*)&w2f[c4 * 4];
      s1 += v.x * u1.x + v.y * u1.y + v.z * u1.z + v.w * u1.w;
      s2 += v.x * u2.x + v.y * u2.y + v.z * u2.z + v.w * u2.w;
      *(float4*)&tile[r][c4 * 4] = v;
    }
#pragma unroll
    for (int off = 4; off >= 1; off >>= 1) {
      s1 += __shfl_xor(s1, off);
      s2 += __shfl_xor(s2, off);
    }
    if (g8 == 0) {
      AxL[b * 4096 + f * 32 + r] = s1 * LOG2E;
      AyL[b * 4096 + f * 32 + r] = s2 * LOG2E;
    }
  }
  __syncthreads();

  {
    const int g = tid >> 4, l15 = tid & 15;
    short* d = featB + (((size_t)((b * 128 + f) * 16 + g)) * 64) * 8;
#pragma unroll
    for (int q = 0; q < 4; ++q) {
      short8 v;
#pragma unroll
      for (int j8 = 0; j8 < 8; ++j8) v[j8] = f2bf(tile[q * 8 + j8][g * 16 + l15]);
      *(short8*)(d + (q * 16 + l15) * 8) = v;
    }
  }

  if (b == 0 && f < 8) {
    const int g = tid >> 4, l15 = tid & 15;
    const float* s = W + ((size_t)f * 32) * 256 + g * 16 + l15;
    short* d = WB + (((size_t)(f * 16 + g)) * 64) * 8;
#pragma unroll
    for (int q = 0; q < 4; ++q) {
      short8 v;
#pragma unroll
      for (int j8 = 0; j8 < 8; ++j8) v[j8] = f2bf(s[(q * 8 + j8) * 256]);
      *(short8*)(d + (q * 16 + l15) * 8) = v;
    }
  }
}

// -------- fused softmax(mask(lrelu(rank1)))@feat @W +ELU --------
// Round-8 structure at DOUBLE OCCUPANCY: 1024-thread blocks (16 waves ->
// 4 waves/SIMD at 1 block/CU, was 2). All data-path levers tested neutral
// (r4/r5/r7/r8); r9's coarser supersteps regressed -> attn is
// latency-structure-bound at 2 waves/SIMD. Per-wave work halves (phase1:
// 4 rows; phase2: 1 col-tile x 4 row-groups -- featB dedup preserved,
// each fragment loaded once per block; epilogue: 16x64 tile), per-CU work
// identical, VGPR per thread halves (fits launch_bounds(1024,4) cap).
// Raw s_barrier + lgkmcnt(0) in-loop; 1-deep adj prefetch; 16x256-j
// supersteps (r9 proved coarser is worse).
__global__ __launch_bounds__(1024, 4) void gat_attn(
    const short* __restrict__ featB,  // [4][128][16][64][8] bf16 fragments
    const int* __restrict__ adj,      // [4][4096][4096]
    const float* __restrict__ AxL, const float* __restrict__ AyL,
    const short* __restrict__ WB,     // [8][16][64][8] bf16 fragments
    float* __restrict__ out)          // [4][4096][256] f32
{
  __shared__ short smem[33792];  // Pbuf[2][64][264]; later aliased as hbuf[64][264]
  __shared__ float mred[16];

  const int tid = threadIdx.x;
  const int blk = blockIdx.x;
  const int x = blk & 7;
  const int b = x >> 1;                       // XCD-pinned batch
  const int it = ((blk >> 3) << 1) | (x & 1); // 0..63
  const int i0 = it << 6;
  const int scoff = (blk >> 3) & 15;          // staggered j-window start

  const int lane = tid & 63;
  const int aw = tid >> 6;                    // wave 0..15
  const int l15 = lane & 15;
  const int q = lane >> 4;

  // ---- per-batch max of AxL ----
  const float* axb = AxL + b * 4096;
  float mx = -3.4e38f;
  for (int i = tid; i < 4096; i += 1024) mx = fmaxf(mx, axb[i]);
#pragma unroll
  for (int off = 32; off >= 1; off >>= 1) mx = fmaxf(mx, __shfl_xor(mx, off));
  if (lane == 0) mred[aw] = mx;
  __syncthreads();
  float MbLb = mred[0];
#pragma unroll
  for (int i = 1; i < 16; ++i) MbLb = fmaxf(MbLb, mred[i]);

  // --- P-producer role: wave owns rows aw*4..aw*4+3; lane owns 4 j's ---
  float aLk[4], ddk[4];
#pragma unroll
  for (int k = 0; k < 4; ++k) {
    float ayL = AyL[b * 4096 + i0 + aw * 4 + k];
    float sL = ayL + MbLb;
    float mrL = fmaxf(sL, 0.2f * sL);
    aLk[k] = ayL - mrL;
    ddk[k] = -0.8f * mrL;
  }
  const int* adjr = adj + ((size_t)(b * 4096 + i0 + aw * 4)) * 4096 + lane * 4;
  const float4* axp = (const float4*)(AxL + b * 4096) + lane;

  // --- MFMA role: wave owns col-tile aw (one), all 4 row-groups ---
  f32x4 acc[4], lac[4];
#pragma unroll
  for (int r = 0; r < 4; ++r) {
    lac[r] = (f32x4){0.f, 0.f, 0.f, 0.f};
    acc[r] = (f32x4){0.f, 0.f, 0.f, 0.f};
  }

  short8 ones;
#pragma unroll
  for (int j = 0; j < 8; ++j) ones[j] = (short)0x3F80;  // bf16 1.0

  const short* fbb = featB + (size_t)b * 128 * 16 * 64 * 8 + lane * 8;

  i32x4 adv[4];
  float4 axv;
  {
    axv = axp[scoff * 64];
#pragma unroll
    for (int k = 0; k < 4; ++k)
      adv[k] = __builtin_nontemporal_load((const i32x4*)(adjr) + (size_t)k * 1024 + scoff * 64);
  }

  for (int sc = 0; sc < 16; ++sc) {
    const int wsc = (scoff + sc) & 15;        // actual j-window this iteration
    const int pb = (sc & 1) * 16896;
    // ---- phase 1: 16 probs (4 rows x 4 j) -> Pbuf ----
    {
      const float* af = (const float*)&axv;
#pragma unroll
      for (int k = 0; k < 4; ++k) {
        unsigned pr[4];
#pragma unroll
        for (int u = 0; u < 4; ++u) {
          float v = af[u] + aLk[k];
          float uu = fmaxf(v, fmaf(0.2f, v, ddk[k]));
          unsigned ub = adv[k][u] > 0 ? __builtin_bit_cast(unsigned, uu) : 0xFF800000u;
          float p = __builtin_amdgcn_exp2f(__builtin_bit_cast(float, ub));
          pr[u] = __builtin_bit_cast(unsigned, p) + 0x8000u;
        }
        u32x2 pw;
        pw[0] = __builtin_amdgcn_perm(pr[1], pr[0], 0x07060302u);
        pw[1] = __builtin_amdgcn_perm(pr[3], pr[2], 0x07060302u);
        *(u32x2*)(smem + pb + (aw * 4 + k) * 264 + lane * 4) = pw;
      }
    }
    asm volatile("s_waitcnt lgkmcnt(0)" ::: "memory");
    __builtin_amdgcn_s_barrier();   // raw: in-flight vmem survives

    // ---- prefetch next window's adj + Ax (hidden under phase 2) ----
    if (sc < 15) {
      const int wn = (scoff + sc + 1) & 15;
      axv = axp[wn * 64];
#pragma unroll
      for (int k = 0; k < 4; ++k)
        adv[k] = __builtin_nontemporal_load((const i32x4*)(adjr) + (size_t)k * 1024 + wn * 64);
    }

    // ---- phase 2: 8 k-steps; wave: 1 col-tile x 4 row-groups ----
#pragma unroll
    for (int h = 0; h < 8; ++h) {
      const int f = wsc * 8 + h;
      const short* fb = fbb + (((size_t)f * 16 + aw) << 9);
      short8 a[4];
#pragma unroll
      for (int r = 0; r < 4; ++r)
        a[r] = *(const short8*)(smem + pb + (r * 16 + l15) * 264 + h * 32 + q * 8);
#pragma unroll
      for (int r = 0; r < 4; ++r)
        lac[r] = __builtin_amdgcn_mfma_f32_16x16x32_bf16(a[r], ones, lac[r], 0, 0, 0);
      short8 bf = *(const short8*)fb;
#pragma unroll
      for (int r = 0; r < 4; ++r)
        acc[r] = __builtin_amdgcn_mfma_f32_16x16x32_bf16(a[r], bf, acc[r], 0, 0, 0);
    }
  }

  // lac[r][reg] = row-sum for row r*16 + q*4 + reg (C/D layout)
  float linv[4][4];
#pragma unroll
  for (int r = 0; r < 4; ++r)
#pragma unroll
    for (int reg = 0; reg < 4; ++reg) {
      float l = lac[r][reg];
      linv[r][reg] = l > 0.f ? 1.f / l : 0.f;
    }

  __syncthreads();   // full barrier (incl. drain) before aliasing smem as hbuf
  short* hbuf = smem;  // [64][264]
#pragma unroll
  for (int r = 0; r < 4; ++r)
#pragma unroll
    for (int reg = 0; reg < 4; ++reg) {
      const int lr = r * 16 + q * 4 + reg;
      hbuf[lr * 264 + aw * 16 + l15] = f2bf(acc[r][reg] * linv[r][reg]);
    }
  __syncthreads();

  // ---- epilogue GEMM: (64x256) @ W, ELU, store; wave = 16-row x 64-col tile ----
  const int rowg16 = (aw & 3) << 4;   // row-tile base: 0/16/32/48
  const int cgrp = (aw >> 2) << 2;    // col-group base in 16-col units: 0,4,8,12

  f32x4 ac2[4];
#pragma unroll
  for (int j = 0; j < 4; ++j) ac2[j] = (f32x4){0.f, 0.f, 0.f, 0.f};

  const short* wbb = WB + lane * 8;
#pragma unroll
  for (int f = 0; f < 8; ++f) {
    short8 a0 = *(const short8*)&hbuf[(rowg16 + l15) * 264 + f * 32 + q * 8];
    const short* wb = wbb + (((size_t)f * 16 + cgrp) << 9);
#pragma unroll
    for (int ct = 0; ct < 4; ++ct) {
      short8 bf = *(const short8*)(wb + (ct << 9));
      ac2[ct] = __builtin_amdgcn_mfma_f32_16x16x32_bf16(a0, bf, ac2[ct], 0, 0, 0);
    }
  }

#pragma unroll
  for (int reg = 0; reg < 4; ++reg) {
    const int row = i0 + rowg16 + q * 4 + reg;
    float* orow = out + ((size_t)(b * 4096 + row)) * 256 + cgrp * 16 + l15;
#pragma unroll
    for (int ct = 0; ct < 4; ++ct) {
      float v = ac2[ct][reg];
      float o = v > 0.f ? v : (__builtin_amdgcn_exp2f(v * LOG2E) - 1.f);
      __builtin_nontemporal_store(o, orow + ct * 16);
    }
  }
}

extern "C" void kernel_launch(void* const* d_in, const int* in_sizes, int n_in,
                              void* d_out, int out_size, void* d_ws, size_t ws_size,
                              hipStream_t stream) {
  (void)in_sizes; (void)n_in; (void)out_size; (void)ws_size;
  const float* feat = (const float*)d_in[0];
  const int* adj = (const int*)d_in[1];
  const float* W = (const float*)d_in[2];
  const float* a1 = (const float*)d_in[3];
  const float* a2 = (const float*)d_in[4];
  float* out = (float*)d_out;

  char* ws = (char*)d_ws;
  short* featB   = (short*)ws;                     // 4*128*16*64*8*2 = 8,388,608 B
  short* WB      = (short*)(ws + 8388608);         // 131,072 B
  float* AxL     = (float*)(ws + 8519680);         // 64 KB
  float* AyL     = (float*)(ws + 8585216);         // 64 KB

  hipLaunchKernelGGL(gat_pro, dim3(128, 4), dim3(256), 0, stream, feat, W, a1, a2, featB, WB, AxL, AyL);
  hipLaunchKernelGGL(gat_attn, dim3(256), dim3(1024), 0, stream, featB, adj, AxL, AyL, WB, out);
}

// Round 11
// 403.146 us; speedup vs baseline: 1.0505x; 1.0217x over previous
//
#include <hip/hip_runtime.h>

typedef __attribute__((ext_vector_type(8))) short short8;
typedef __attribute__((ext_vector_type(4))) float f32x4;
typedef __attribute__((ext_vector_type(4))) int i32x4;
typedef __attribute__((ext_vector_type(2))) unsigned u32x2;

#define LOG2E 1.44269504f

__device__ __forceinline__ short f2bf(float f) {
  unsigned u = __builtin_bit_cast(unsigned, f);
  u += 0x7fffu + ((u >> 16) & 1u);   // round-to-nearest-even
  return (short)(u >> 16);
}

// ---------------- fused prologue (round-2 version) ----------------
__global__ __launch_bounds__(256) void gat_pro(
    const float* __restrict__ feat, const float* __restrict__ W,
    const float* __restrict__ a1, const float* __restrict__ a2,
    short* __restrict__ featB, short* __restrict__ WB,
    float* __restrict__ AxL, float* __restrict__ AyL) {
  __shared__ __align__(16) float a1f[256], a2f[256];
  __shared__ __align__(16) float w1f[256], w2f[256];
  __shared__ __align__(16) float tile[32][260];
  const int tid = threadIdx.x;
  const int f = blockIdx.x, b = blockIdx.y;

  a1f[tid] = a1[tid];
  a2f[tid] = a2[tid];
  __syncthreads();

  {
    float s1 = 0.f, s2 = 0.f;
    const float4* wr = (const float4*)(W + (size_t)tid * 256);
    for (int d0 = 0; d0 < 64; ++d0) {
      float4 v = wr[d0];
      s1 += v.x * a1f[d0 * 4] + v.y * a1f[d0 * 4 + 1] + v.z * a1f[d0 * 4 + 2] + v.w * a1f[d0 * 4 + 3];
      s2 += v.x * a2f[d0 * 4] + v.y * a2f[d0 * 4 + 1] + v.z * a2f[d0 * 4 + 2] + v.w * a2f[d0 * 4 + 3];
    }
    w1f[tid] = s1;
    w2f[tid] = s2;
  }
  __syncthreads();

  {
    const int r = tid >> 3, g8 = tid & 7;
    const float* frow = feat + ((size_t)(b * 4096 + f * 32 + r)) * 256;
    float s1 = 0.f, s2 = 0.f;
#pragma unroll
    for (int k = 0; k < 8; ++k) {
      const int c4 = g8 + 8 * k;
      float4 v = *(const float4*)(frow + c4 * 4);
      float4 u1 = *(const float4*)&w1f[c4 * 4];
      float4 u2 = *(const float4*)&w2f[c4 * 4];
      s1 += v.x * u1.x + v.y * u1.y + v.z * u1.z + v.w * u1.w;
      s2 += v.x * u2.x + v.y * u2.y + v.z * u2.z + v.w * u2.w;
      *(float4*)&tile[r][c4 * 4] = v;
    }
#pragma unroll
    for (int off = 4; off >= 1; off >>= 1) {
      s1 += __shfl_xor(s1, off);
      s2 += __shfl_xor(s2, off);
    }
    if (g8 == 0) {
      AxL[b * 4096 + f * 32 + r] = s1 * LOG2E;
      AyL[b * 4096 + f * 32 + r] = s2 * LOG2E;
    }
  }
  __syncthreads();

  {
    const int g = tid >> 4, l15 = tid & 15;
    short* d = featB + (((size_t)((b * 128 + f) * 16 + g)) * 64) * 8;
#pragma unroll
    for (int q = 0; q < 4; ++q) {
      short8 v;
#pragma unroll
      for (int j8 = 0; j8 < 8; ++j8) v[j8] = f2bf(tile[q * 8 + j8][g * 16 + l15]);
      *(short8*)(d + (q * 16 + l15) * 8) = v;
    }
  }

  if (b == 0 && f < 8) {
    const int g = tid >> 4, l15 = tid & 15;
    const float* s = W + ((size_t)f * 32) * 256 + g * 16 + l15;
    short* d = WB + (((size_t)(f * 16 + g)) * 64) * 8;
#pragma unroll
    for (int q = 0; q < 4; ++q) {
      short8 v;
#pragma unroll
      for (int j8 = 0; j8 < 8; ++j8) v[j8] = f2bf(s[(q * 8 + j8) * 256]);
      *(short8*)(d + (q * 16 + l15) * 8) = v;
    }
  }
}

// -------- fused softmax(mask(lrelu(rank1)))@feat @W +ELU --------
// ROUND-8 CONFIGURATION (best measured: 406.8 us total) — final revert.
// 64-row blocks, 8 waves (2/SIMD), featB dedup (wave = 2 col-tiles x 4
// row-groups, every fragment loaded once per block), register-prefetched
// featB (fbr holds next superstep's fragments), raw s_barrier+lgkmcnt(0)
// in-loop (in-flight vmem survives barriers), 1-deep adj prefetch,
// 16 supersteps of 256 j with staggered start.
__global__ __launch_bounds__(512, 2) void gat_attn(
    const short* __restrict__ featB,  // [4][128][16][64][8] bf16 fragments
    const int* __restrict__ adj,      // [4][4096][4096]
    const float* __restrict__ AxL, const float* __restrict__ AyL,
    const short* __restrict__ WB,     // [8][16][64][8] bf16 fragments
    float* __restrict__ out)          // [4][4096][256] f32
{
  __shared__ short smem[33792];  // Pbuf[2][64][264]; later aliased as hbuf[64][264]
  __shared__ float mred[8];

  const int tid = threadIdx.x;
  const int blk = blockIdx.x;
  const int x = blk & 7;
  const int b = x >> 1;                       // XCD-pinned batch
  const int it = ((blk >> 3) << 1) | (x & 1); // 0..63
  const int i0 = it << 6;
  const int scoff = (blk >> 3) & 15;          // staggered j-window start

  const int lane = tid & 63;
  const int aw = tid >> 6;                    // wave 0..7

  // ---- per-batch max of AxL ----
  const float* axb = AxL + b * 4096;
  float mx = -3.4e38f;
  for (int i = tid; i < 4096; i += 512) mx = fmaxf(mx, axb[i]);
#pragma unroll
  for (int off = 32; off >= 1; off >>= 1) mx = fmaxf(mx, __shfl_xor(mx, off));
  if (lane == 0) mred[aw] = mx;
  __syncthreads();
  const float MbLb = fmaxf(fmaxf(fmaxf(mred[0], mred[1]), fmaxf(mred[2], mred[3])),
                           fmaxf(fmaxf(mred[4], mred[5]), fmaxf(mred[6], mred[7])));

  // --- P-producer role: wave owns rows aw*8..aw*8+7; lane owns 4 j's ---
  float aLk[8], ddk[8];
#pragma unroll
  for (int k = 0; k < 8; ++k) {
    float ayL = AyL[b * 4096 + i0 + aw * 8 + k];
    float sL = ayL + MbLb;
    float mrL = fmaxf(sL, 0.2f * sL);
    aLk[k] = ayL - mrL;
    ddk[k] = -0.8f * mrL;
  }
  const int* adjr = adj + ((size_t)(b * 4096 + i0 + aw * 8)) * 4096 + lane * 4;
  const float4* axp = (const float4*)(AxL + b * 4096) + lane;

  // --- MFMA role: wave owns col-tiles g in {2*aw, 2*aw+1}, all 4 row-groups ---
  const int cg2 = aw << 1;
  const int l15 = lane & 15;
  const int q = lane >> 4;

  f32x4 acc[4][2], lac[4];
#pragma unroll
  for (int r = 0; r < 4; ++r) {
    lac[r] = (f32x4){0.f, 0.f, 0.f, 0.f};
#pragma unroll
    for (int j = 0; j < 2; ++j) acc[r][j] = (f32x4){0.f, 0.f, 0.f, 0.f};
  }

  short8 ones;
#pragma unroll
  for (int j = 0; j < 8; ++j) ones[j] = (short)0x3F80;  // bf16 1.0

  const short* fbb = featB + (size_t)b * 128 * 16 * 64 * 8 + lane * 8;

  i32x4 adv[8];
  float4 axv;
  short8 fbr[8][2];   // next-superstep featB fragments (64 VGPR)

  // ---- pre-loop: adj/Ax window scoff + featB fragments for window scoff ----
  {
    axv = axp[scoff * 64];
#pragma unroll
    for (int k = 0; k < 8; ++k)
      adv[k] = __builtin_nontemporal_load((const i32x4*)(adjr) + (size_t)k * 1024 + scoff * 64);
#pragma unroll
    for (int h = 0; h < 8; ++h) {
      const short* fb = fbb + (((size_t)((scoff * 8 + h) * 16 + cg2)) << 9);
#pragma unroll
      for (int ct = 0; ct < 2; ++ct)
        fbr[h][ct] = *(const short8*)(fb + (ct << 9));
    }
  }

  for (int sc = 0; sc < 16; ++sc) {
    const int pb = (sc & 1) * 16896;
    // ---- phase 1: 32 probs (8 rows x 4 j) -> Pbuf ----
    {
      const float* af = (const float*)&axv;
#pragma unroll
      for (int k = 0; k < 8; ++k) {
        unsigned pr[4];
#pragma unroll
        for (int u = 0; u < 4; ++u) {
          float v = af[u] + aLk[k];
          float uu = fmaxf(v, fmaf(0.2f, v, ddk[k]));
          unsigned ub = adv[k][u] > 0 ? __builtin_bit_cast(unsigned, uu) : 0xFF800000u;
          float p = __builtin_amdgcn_exp2f(__builtin_bit_cast(float, ub));
          pr[u] = __builtin_bit_cast(unsigned, p) + 0x8000u;
        }
        u32x2 pw;
        pw[0] = __builtin_amdgcn_perm(pr[1], pr[0], 0x07060302u);
        pw[1] = __builtin_amdgcn_perm(pr[3], pr[2], 0x07060302u);
        *(u32x2*)(smem + pb + (aw * 8 + k) * 264 + lane * 4) = pw;
      }
    }
    asm volatile("s_waitcnt lgkmcnt(0)" ::: "memory");
    __builtin_amdgcn_s_barrier();   // raw: featB/adj loads stay in flight

    // ---- prefetch next window's adj + Ax (1-deep; hidden under phase 2) ----
    if (sc < 15) {
      const int wn = (scoff + sc + 1) & 15;
      axv = axp[wn * 64];
#pragma unroll
      for (int k = 0; k < 8; ++k)
        adv[k] = __builtin_nontemporal_load((const i32x4*)(adjr) + (size_t)k * 1024 + wn * 64);
    }

    // ---- phase 2: consume fbr (loaded last superstep), reload for next ----
    {
      const int wnx = (scoff + sc + 1) & 15;   // sc=15 reloads scoff (unused, valid addr)
#pragma unroll
      for (int h = 0; h < 8; ++h) {
        const short* fbn = fbb + (((size_t)((wnx * 8 + h) * 16 + cg2)) << 9);
        short8 a[4];
#pragma unroll
        for (int r = 0; r < 4; ++r)
          a[r] = *(const short8*)(smem + pb + (r * 16 + l15) * 264 + h * 32 + q * 8);
#pragma unroll
        for (int r = 0; r < 4; ++r)
          lac[r] = __builtin_amdgcn_mfma_f32_16x16x32_bf16(a[r], ones, lac[r], 0, 0, 0);
#pragma unroll
        for (int ct = 0; ct < 2; ++ct) {
          short8 bf = fbr[h][ct];
#pragma unroll
          for (int r = 0; r < 4; ++r)
            acc[r][ct] = __builtin_amdgcn_mfma_f32_16x16x32_bf16(a[r], bf, acc[r][ct], 0, 0, 0);
          fbr[h][ct] = *(const short8*)(fbn + (ct << 9));   // reload for sc+1
        }
      }
    }
  }

  // lac[r][reg] = row-sum for row r*16 + q*4 + reg (C/D layout)
  float linv[4][4];
#pragma unroll
  for (int r = 0; r < 4; ++r)
#pragma unroll
    for (int reg = 0; reg < 4; ++reg) {
      float l = lac[r][reg];
      linv[r][reg] = l > 0.f ? 1.f / l : 0.f;
    }

  __syncthreads();   // full barrier (incl. drain) before aliasing smem as hbuf
  short* hbuf = smem;  // [64][264]
#pragma unroll
  for (int r = 0; r < 4; ++r)
#pragma unroll
    for (int reg = 0; reg < 4; ++reg) {
      const int lr = r * 16 + q * 4 + reg;
#pragma unroll
      for (int ct = 0; ct < 2; ++ct)
        hbuf[lr * 264 + (cg2 + ct) * 16 + l15] = f2bf(acc[r][ct][reg] * linv[r][reg]);
    }
  __syncthreads();

  // ---- epilogue GEMM: (64x256) @ W, ELU, store (round-2 roles) ----
  const int rowg = (aw & 1) << 4;    // 0/16; second group is +32
  const int cgrp = (aw >> 1) << 2;   // col-group base in 16-col units

  f32x4 ac2[2][4];
#pragma unroll
  for (int r = 0; r < 2; ++r)
#pragma unroll
    for (int j = 0; j < 4; ++j) ac2[r][j] = (f32x4){0.f, 0.f, 0.f, 0.f};

  const short* wbb = WB + lane * 8;
#pragma unroll
  for (int f = 0; f < 8; ++f) {
    short8 a0 = *(const short8*)&hbuf[(rowg + l15) * 264 + f * 32 + q * 8];
    short8 a1 = *(const short8*)&hbuf[(rowg + 32 + l15) * 264 + f * 32 + q * 8];
    const short* wb = wbb + (((size_t)f * 16 + cgrp) << 9);
#pragma unroll
    for (int ct = 0; ct < 4; ++ct) {
      short8 bf = *(const short8*)(wb + (ct << 9));
      ac2[0][ct] = __builtin_amdgcn_mfma_f32_16x16x32_bf16(a0, bf, ac2[0][ct], 0, 0, 0);
      ac2[1][ct] = __builtin_amdgcn_mfma_f32_16x16x32_bf16(a1, bf, ac2[1][ct], 0, 0, 0);
    }
  }

#pragma unroll
  for (int r = 0; r < 2; ++r)
#pragma unroll
    for (int reg = 0; reg < 4; ++reg) {
      const int row = i0 + rowg + r * 32 + q * 4 + reg;
      float* orow = out + ((size_t)(b * 4096 + row)) * 256 + cgrp * 16 + l15;
#pragma unroll
      for (int ct = 0; ct < 4; ++ct) {
        float v = ac2[r][ct][reg];
        float o = v > 0.f ? v : (__builtin_amdgcn_exp2f(v * LOG2E) - 1.f);
        __builtin_nontemporal_store(o, orow + ct * 16);
      }
    }
}

extern "C" void kernel_launch(void* const* d_in, const int* in_sizes, int n_in,
                              void* d_out, int out_size, void* d_ws, size_t ws_size,
                              hipStream_t stream) {
  (void)in_sizes; (void)n_in; (void)out_size; (void)ws_size;
  const float* feat = (const float*)d_in[0];
  const int* adj = (const int*)d_in[1];
  const float* W = (const float*)d_in[2];
  const float* a1 = (const float*)d_in[3];
  const float* a2 = (const float*)d_in[4];
  float* out = (float*)d_out;

  char* ws = (char*)d_ws;
  short* featB   = (short*)ws;                     // 4*128*16*64*8*2 = 8,388,608 B
  short* WB      = (short*)(ws + 8388608);         // 131,072 B
  float* AxL     = (float*)(ws + 8519680);         // 64 KB
  float* AyL     = (float*)(ws + 8585216);         // 64 KB

  hipLaunchKernelGGL(gat_pro, dim3(128, 4), dim3(256), 0, stream, feat, W, a1, a2, featB, WB, AxL, AyL);
  hipLaunchKernelGGL(gat_attn, dim3(256), dim3(512), 0, stream, featB, adj, AxL, AyL, WB, out);
}